// Round 7
// baseline (137.650 us; speedup 1.0000x reference)
//
#include <hip/hip_runtime.h>

// CoPE: gated reverse-cumsum positions + interpolated positional logits.
// B=2,H=16,S=2048,D=64,NPOS=64 -> 65536 rows of length 2048.
//
// R6 CONFIRMED: normal stores write-allocate on gfx950 (~537MB hidden
// fetch); __builtin_nontemporal_store removed it: 164.7 -> 105.4 us.
// Floor arithmetic: 537MB W + ~66MB R at fill-proven 6.7 TB/s ~ 90 us.
//
// R7: squeeze the remaining 15%:
//  - 4 rows/wave, all 12 chunk loads + q prefetched upfront (overlap)
//  - einsum via WAVE-UNIFORM scalar q loads (s_load) -> zero DS shuffles
//    (q + r*64 is wave-uniform; emb[d*64+lane] is L1-resident)
//  - parallel 3-chunk scan chains (6-step loop, 3 chains)
//  - nontemporal loads on streamed attn chunks, NT stores everywhere

#define SLEN 2048
#define DDIM 64
#define NPOSN 64
#define ROWS (2 * 16 * 2048)
#define RPW 4

typedef float vfloat4 __attribute__((ext_vector_type(4)));

__device__ __forceinline__ float sigmoidf_(float x) {
    return 1.0f / (1.0f + __expf(-x));
}

__global__ __launch_bounds__(256) void cope_kernel(
    const float* __restrict__ q,     // [65536, 64]
    const float* __restrict__ attn,  // [65536, 2048]
    const float* __restrict__ emb,   // [64, 64]
    float* __restrict__ out)         // [65536, 2048]
{
    const int lane = threadIdx.x & 63;
    const int wave = threadIdx.x >> 6;
    const int r0 = (blockIdx.x * 4 + wave) * RPW;

    // ---- upfront: 12 streamed chunk loads (latencies overlap) ----
    float c[RPW][3];
    #pragma unroll
    for (int i = 0; i < RPW; ++i) {
        const float* __restrict__ arow = attn + (size_t)(r0 + i) * SLEN;
        c[i][0] = __builtin_nontemporal_load(arow + SLEN -  64 + lane);
        c[i][1] = __builtin_nontemporal_load(arow + SLEN - 128 + lane);
        c[i][2] = __builtin_nontemporal_load(arow + SLEN - 192 + lane);
    }

    // ---- einsum: lv[i][lane] = sum_d q[r][d] * emb[d][lane] ----
    // q row address is wave-uniform -> s_load; emb is 16KB, L1-resident.
    float lv[RPW];
    #pragma unroll
    for (int i = 0; i < RPW; ++i) {
        const float* __restrict__ qrow = q + (size_t)(r0 + i) * DDIM;
        float a0 = 0.0f, a1 = 0.0f;
        #pragma unroll
        for (int d = 0; d < DDIM; d += 2) {
            a0 = fmaf(qrow[d],     emb[d * NPOSN + lane],       a0);
            a1 = fmaf(qrow[d + 1], emb[(d + 1) * NPOSN + lane], a1);
        }
        lv[i] = a0 + a1;
    }

    #pragma unroll
    for (int i = 0; i < RPW; ++i) {
        const float lvi = lv[i];
        float* __restrict__ orow = out + (size_t)(r0 + i) * SLEN;

        // three independent reverse inclusive scans, one 6-step loop
        float s0 = sigmoidf_(c[i][0]);
        float s1 = sigmoidf_(c[i][1]);
        float s2 = sigmoidf_(c[i][2]);
        #pragma unroll
        for (int off = 1; off < 64; off <<= 1) {
            const float t0 = __shfl_down(s0, off);
            const float t1 = __shfl_down(s1, off);
            const float t2 = __shfl_down(s2, off);
            if (lane + off < 64) { s0 += t0; s1 += t1; s2 += t2; }
        }
        const float T0 = __shfl(s0, 0);
        const float T1 = __shfl(s1, 0);
        const float T2 = __shfl(s2, 0);

        {
            const float pos = fminf(s0, 63.0f);
            const float pf = floorf(pos), w = pos - pf;
            const float lf = __shfl(lvi, (int)pf);
            const float lc = __shfl(lvi, (int)ceilf(pos));
            __builtin_nontemporal_store(lc * w + lf * (1.0f - w),
                                        orow + SLEN - 64 + lane);
        }
        {
            const float pos = fminf(T0 + s1, 63.0f);
            const float pf = floorf(pos), w = pos - pf;
            const float lf = __shfl(lvi, (int)pf);
            const float lc = __shfl(lvi, (int)ceilf(pos));
            __builtin_nontemporal_store(lc * w + lf * (1.0f - w),
                                        orow + SLEN - 128 + lane);
        }
        {
            const float pos = fminf(T0 + T1 + s2, 63.0f);
            const float pf = floorf(pos), w = pos - pf;
            const float lf = __shfl(lvi, (int)pf);
            const float lc = __shfl(lvi, (int)ceilf(pos));
            __builtin_nontemporal_store(lc * w + lf * (1.0f - w),
                                        orow + SLEN - 192 + lane);
        }

        float carry = T0 + T1 + T2;
        int jb = SLEN - 192;

        // slow path (P ~ 0 for this data; correctness only)
        const float* __restrict__ arow = attn + (size_t)(r0 + i) * SLEN;
        while (carry < 63.0f && jb > 0) {
            jb -= 64;
            float s = sigmoidf_(arow[jb + lane]);
            #pragma unroll
            for (int off = 1; off < 64; off <<= 1) {
                const float t = __shfl_down(s, off);
                if (lane + off < 64) s += t;
            }
            const float pos = fminf(carry + s, 63.0f);
            const float pf = floorf(pos), w = pos - pf;
            const float lf = __shfl(lvi, (int)pf);
            const float lc = __shfl(lvi, (int)ceilf(pos));
            __builtin_nontemporal_store(lc * w + lf * (1.0f - w),
                                        orow + jb + lane);
            carry += __shfl(s, 0);
        }

        // fill [0, jb) with logits_int[63] (pos clamps -> w == 0)
        const float l63 = __shfl(lvi, NPOSN - 1);
        const vfloat4 v4 = { l63, l63, l63, l63 };
        for (int j = lane * 4; j < jb; j += 256)
            __builtin_nontemporal_store(v4, reinterpret_cast<vfloat4*>(orow + j));
    }
}

extern "C" void kernel_launch(void* const* d_in, const int* in_sizes, int n_in,
                              void* d_out, int out_size, void* d_ws, size_t ws_size,
                              hipStream_t stream) {
    const float* q    = (const float*)d_in[0];
    const float* attn = (const float*)d_in[1];
    const float* emb  = (const float*)d_in[2];
    float* out = (float*)d_out;

    dim3 grid(ROWS / (4 * RPW)), block(256);
    cope_kernel<<<grid, block, 0, stream>>>(q, attn, emb, out);
}

// Round 8
// 101.544 us; speedup vs baseline: 1.3556x; 1.3556x over previous
//
#include <hip/hip_runtime.h>

// CoPE: gated reverse-cumsum positions + interpolated positional logits.
// B=2,H=16,S=2048,D=64,NPOS=64 -> 65536 rows of length 2048.
//
// R6 CONFIRMED write-allocate: NT stores took 164.7 -> 105.4 us.
// R7 FAILED (137.6): q "scalar" loads weren't provably wave-uniform ->
// 256 per-lane VMEM broadcasts; RPW=4 shrank the grid; NT loads unvetted.
//
// R8 (on R6 base, floor ~90 us at fill-proven 6.7 TB/s):
//  - emb staged in LDS (einsum reads leave the VMEM pipe; 2-way bank = free)
//  - q row via readfirstlane-forced SGPR base -> true s_load, no shuffles
//  - 256-col scan pass: lane owns 4 cols (float4), per-lane local suffix +
//    one 6-step wave scan of totals; whole unclamped region in ONE pass,
//    one NT float4 store per lane (was 3 serial chunk passes)
//  - unchanged from R6: 1 row/wave, 16384 blocks, cached attn loads, NT stores

#define SLEN 2048
#define DDIM 64
#define NPOSN 64
#define ROWS (2 * 16 * 2048)
#define CH 256                  // columns per scan pass (4 per lane)

typedef float vfloat4 __attribute__((ext_vector_type(4)));

__device__ __forceinline__ float sigmoidf_(float x) {
    return 1.0f / (1.0f + __expf(-x));
}

__global__ __launch_bounds__(256) void cope_kernel(
    const float* __restrict__ q,     // [65536, 64]
    const float* __restrict__ attn,  // [65536, 2048]
    const float* __restrict__ emb,   // [64, 64]
    float* __restrict__ out)         // [65536, 2048]
{
    __shared__ float semb[DDIM * NPOSN];   // 16 KiB
    {
        const float4* __restrict__ src = (const float4*)emb;
        float4* __restrict__ dst = (float4*)semb;
        #pragma unroll
        for (int t = 0; t < 4; ++t)
            dst[threadIdx.x + 256 * t] = src[threadIdx.x + 256 * t];
    }
    __syncthreads();

    const int lane = threadIdx.x & 63;
    const int wave = threadIdx.x >> 6;
    const int r_u = __builtin_amdgcn_readfirstlane(blockIdx.x * 4 + wave);

    const float* __restrict__ arow = attn + (size_t)r_u * SLEN;
    float* __restrict__ orow = out + (size_t)r_u * SLEN;

    // prefetch first scan chunk: cols [SLEN-CH, SLEN), 4 consecutive per lane
    float4 cur = *reinterpret_cast<const float4*>(arow + SLEN - CH + lane * 4);

    // einsum while the load is in flight:
    // lv = logits_int[r][lane] = sum_d q[r][d] * emb[d][lane]
    // qrow[d] is a true s_load (r_u is SGPR); semb read is DS, 2-way banked.
    const float* __restrict__ qrow = q + (size_t)r_u * DDIM;
    float a0 = 0.0f, a1 = 0.0f;
    #pragma unroll
    for (int d = 0; d < DDIM; d += 2) {
        a0 = fmaf(qrow[d],     semb[d * NPOSN + lane],       a0);
        a1 = fmaf(qrow[d + 1], semb[(d + 1) * NPOSN + lane], a1);
    }
    const float lv  = a0 + a1;
    const float l63 = __shfl(lv, NPOSN - 1);

    float carry = 0.0f;
    int jb = SLEN;
    for (;;) {
        const int base = jb - CH;
        // gates
        const float g0 = sigmoidf_(cur.x);
        const float g1 = sigmoidf_(cur.y);
        const float g2 = sigmoidf_(cur.z);
        const float g3 = sigmoidf_(cur.w);
        // per-lane local reverse suffices
        const float l3 = g3;
        const float l2 = g2 + l3;
        const float l1 = g1 + l2;
        const float l0 = g0 + l1;          // lane total
        // wave reverse inclusive scan of lane totals
        float s = l0;
        #pragma unroll
        for (int off = 1; off < 64; off <<= 1) {
            const float t = __shfl_down(s, off);
            if (lane + off < 64) s += t;
        }
        const float excl = carry + (s - l0);   // suffix strictly right of lane
        const float T    = __shfl(s, 0);       // chunk total

        vfloat4 o;
        {
            const float pos = fminf(excl + l0, 63.0f);
            const float pf = floorf(pos), w = pos - pf;
            o.x = __shfl(lv, (int)ceilf(pos)) * w + __shfl(lv, (int)pf) * (1.0f - w);
        }
        {
            const float pos = fminf(excl + l1, 63.0f);
            const float pf = floorf(pos), w = pos - pf;
            o.y = __shfl(lv, (int)ceilf(pos)) * w + __shfl(lv, (int)pf) * (1.0f - w);
        }
        {
            const float pos = fminf(excl + l2, 63.0f);
            const float pf = floorf(pos), w = pos - pf;
            o.z = __shfl(lv, (int)ceilf(pos)) * w + __shfl(lv, (int)pf) * (1.0f - w);
        }
        {
            const float pos = fminf(excl + l3, 63.0f);
            const float pf = floorf(pos), w = pos - pf;
            o.w = __shfl(lv, (int)ceilf(pos)) * w + __shfl(lv, (int)pf) * (1.0f - w);
        }
        __builtin_nontemporal_store(o, reinterpret_cast<vfloat4*>(orow + base + lane * 4));

        carry += T;
        jb = base;
        if (carry >= 63.0f || jb == 0) break;
        // slow path (P ~ 0 for random data; correctness only)
        cur = *reinterpret_cast<const float4*>(arow + jb - CH + lane * 4);
    }

    // fill [0, jb) with logits_int[63] (pos clamps -> w == 0)
    const vfloat4 v4 = { l63, l63, l63, l63 };
    for (int j = lane * 4; j < jb; j += 256)
        __builtin_nontemporal_store(v4, reinterpret_cast<vfloat4*>(orow + j));
}

extern "C" void kernel_launch(void* const* d_in, const int* in_sizes, int n_in,
                              void* d_out, int out_size, void* d_ws, size_t ws_size,
                              hipStream_t stream) {
    const float* q    = (const float*)d_in[0];
    const float* attn = (const float*)d_in[1];
    const float* emb  = (const float*)d_in[2];
    float* out = (float*)d_out;

    dim3 grid(ROWS / 4), block(256);
    cope_kernel<<<grid, block, 0, stream>>>(q, attn, emb, out);
}